// Round 7
// baseline (286.885 us; speedup 1.0000x reference)
//
#include <hip/hip_runtime.h>
#include <hip/hip_bf16.h>
#include <cstdint>

// ============================================================================
// MultiHeadSelfAttention: B=8 T=1024 D=1024 H=16 dh=64. fp32 in / fp32 out.
// R14: GEMM1 ported to the 256^2 8-phase schedule (R13 post-mortem: occupancy
// +60% and FETCH -40% moved duration 0% -> schedule-bound at the 2-phase
// ceiling, 636 TF == m233/m248's 2ph number. Only measured escape: T3+T4+T5
// 8-phase, m201: 1563 TF @4k).
//  gemm_qkv_8phase: BM=BN=256, BK=64, 512 thr (2Mx4N waves, 128x64/wave),
//  LDS 128KB (2 slots x A/B x 2 halves x 128x64 bf16). Slot0=even K-tiles,
//  slot1=odd. P1-4 consume t=2i, P5-8 consume t=2i+1. Stage 1 half-tile per
//  phase: P1/2->A(2i+1), P3/4->B(2i+2), P5/6->A(2i+2), P7/8->B(2i+3); every
//  target freed >=1 barrier-phase before overwrite (B reg-loaded in its
//  K-tile's first phase; A consumed progressively to P4). vmcnt(4) at P4/P8
//  drains exactly the next half-iteration's operands (invariant: 4 loads in
//  flight). Prologue 12 loads + vmcnt(4); final iter stages A(15) only,
//  vmcnt(0). T2 both-sides swizzle + fragment layout verbatim from R13.
//  GEMM3 keeps R13's 2-phase 128^2 kernel; attn/cvt unchanged.
// ws (64MiB): Qp@0, Kp@16MiB, Vt@32MiB, aout@48MiB (each [8192][1024] bf16).
// d_out scratch phase 1: ib_bf@0 (16MiB), wq_bf@16MiB (6MiB), bq_bf@22MiB.
// After attn: wo_bf/bo_bf overwrite dead Qp@0. GEMM3 writes d_out fp32 last.
// ============================================================================

using bf16 = __hip_bfloat16;
typedef __attribute__((ext_vector_type(8))) short short8;
typedef __attribute__((ext_vector_type(4))) short short4v;
typedef __attribute__((ext_vector_type(4))) float floatx4;
typedef __attribute__((ext_vector_type(2))) unsigned int uint2v;

#define B_    8
#define T_    1024
#define D_    1024
#define H_    16
#define PROJW 3072

__device__ __forceinline__ void gl2lds16(const void* g, void* l) {
  __builtin_amdgcn_global_load_lds(
      (const __attribute__((address_space(1))) void*)g,
      (__attribute__((address_space(3))) void*)l,
      16, 0, 0);
}

__device__ __forceinline__ unsigned short f2b_bits(float f) {
  return __builtin_bit_cast(unsigned short, __float2bfloat16(f));
}

// raw v_exp_f32 (1 ulp), bypassing the OCML exp2f range-fixup path
__device__ __forceinline__ float fast_exp2(float x) {
#if __has_builtin(__builtin_amdgcn_exp2f)
  return __builtin_amdgcn_exp2f(x);
#else
  float r;
  asm("v_exp_f32 %0, %1\ns_nop 0" : "=v"(r) : "v"(x));
  return r;
#endif
}

// ---------------------------------------------------------------------------
// fp32 -> bf16 elementwise convert (n multiple of 4), RNE
// ---------------------------------------------------------------------------
__global__ __launch_bounds__(256)
void cvt_f32_bf16(const float* __restrict__ src, bf16* __restrict__ dst, int n) {
  int i = (blockIdx.x * 256 + threadIdx.x) * 4;
  if (i < n) {
    floatx4 f = *(const floatx4*)(src + i);
    short4v h;
    h[0] = f2b_bits(f[0]); h[1] = f2b_bits(f[1]);
    h[2] = f2b_bits(f[2]); h[3] = f2b_bits(f[3]);
    *(short4v*)(dst + i) = h;
  }
}

// ---------------------------------------------------------------------------
// R14 GEMM1: QKV projection, 256x256 tile, 8-phase schedule (see header).
// A[8192,1024] bf16, Bm[3072,1024] bf16 (row-major N,K), bias bf16.
// grid (12, 32), 512 threads. Output split: Qp / Kp / Vt (transposed).
// ---------------------------------------------------------------------------
#define STAGE_A(T, HALF, SLOT) do {                                            \
    gl2lds16(pA[HALF][0] + (size_t)(T) * 64, &sA[SLOT][(HALF) * 8192 + lds0]); \
    gl2lds16(pA[HALF][1] + (size_t)(T) * 64, &sA[SLOT][(HALF) * 8192 + lds1]); \
  } while (0)
#define STAGE_B(T, HALF, SLOT) do {                                            \
    gl2lds16(pB[HALF][0] + (size_t)(T) * 64, &sB[SLOT][(HALF) * 8192 + lds0]); \
    gl2lds16(pB[HALF][1] + (size_t)(T) * 64, &sB[SLOT][(HALF) * 8192 + lds1]); \
  } while (0)
#define VMCNT_T do {                                                           \
    if (st) asm volatile("s_waitcnt vmcnt(4)" ::: "memory");                   \
    else    asm volatile("s_waitcnt vmcnt(0)" ::: "memory");                   \
  } while (0)

#define PHASE(Q, CS, STG, VMW) do {                                            \
    if ((Q) == 0) {                                                            \
      _Pragma("unroll")                                                        \
      for (int nj = 0; nj < 4; ++nj)                                           \
        _Pragma("unroll")                                                      \
        for (int kq = 0; kq < 2; ++kq)                                         \
          breg[nj][kq] = *(const short8*)&sB[CS][boffc + nj * 1024 +           \
                                                 ((kq * 32 + qoff) ^ swx)];    \
    }                                                                          \
    short8 areg[2][2];                                                         \
    _Pragma("unroll")                                                          \
    for (int mi2 = 0; mi2 < 2; ++mi2)                                          \
      _Pragma("unroll")                                                        \
      for (int kq = 0; kq < 2; ++kq)                                           \
        areg[mi2][kq] = *(const short8*)&sA[CS][aoffc + ((Q) * 2 + mi2) * 1024 \
                                                + ((kq * 32 + qoff) ^ swx)];   \
    STG;                                                                       \
    __builtin_amdgcn_sched_barrier(0);                                         \
    __builtin_amdgcn_s_barrier();                                              \
    asm volatile("s_waitcnt lgkmcnt(0)" ::: "memory");                         \
    __builtin_amdgcn_sched_barrier(0);                                         \
    __builtin_amdgcn_s_setprio(1);                                             \
    _Pragma("unroll")                                                          \
    for (int kq = 0; kq < 2; ++kq)                                             \
      _Pragma("unroll")                                                        \
      for (int mi2 = 0; mi2 < 2; ++mi2)                                        \
        _Pragma("unroll")                                                      \
        for (int nj = 0; nj < 4; ++nj)                                         \
          acc[(Q) * 2 + mi2][nj] = __builtin_amdgcn_mfma_f32_16x16x32_bf16(    \
              areg[mi2][kq], breg[nj][kq], acc[(Q) * 2 + mi2][nj], 0, 0, 0);   \
    __builtin_amdgcn_s_setprio(0);                                             \
    VMW;                                                                       \
    __builtin_amdgcn_sched_barrier(0);                                         \
    __builtin_amdgcn_s_barrier();                                              \
  } while (0)

__global__ __launch_bounds__(512)
void gemm_qkv_8phase(const bf16* __restrict__ A, const bf16* __restrict__ Bm,
                     const bf16* __restrict__ bias, bf16* __restrict__ Qp,
                     bf16* __restrict__ Kp, bf16* __restrict__ Vt)
{
  __shared__ __align__(16) unsigned short sA[2][256 * 64];   // 64 KB
  __shared__ __align__(16) unsigned short sB[2][256 * 64];   // 64 KB

  const int tid  = threadIdx.x;
  const int lane = tid & 63;
  const int wv   = tid >> 6;          // 0..7
  const int quad = lane >> 4;
  const int l16  = lane & 15;
  const int wm   = wv >> 2;           // 0..1: 128-row band (= A half)
  const int wn   = wv & 3;            // 0..3: 64-col band

  // T1 XCD-chunked swizzle: nwg=384 (%8==0); 48 blocks/XCD, bn-fastest.
  const int bidl = blockIdx.y * 12 + blockIdx.x;
  const int swz  = (bidl & 7) * 48 + (bidl >> 3);
  const int bm   = swz / 12, bn = swz % 12;

  floatx4 acc[8][4];
#pragma unroll
  for (int i = 0; i < 8; ++i)
#pragma unroll
    for (int j = 0; j < 4; ++j) acc[i][j] = (floatx4){0.f, 0.f, 0.f, 0.f};

  // staging geometry (T2 rule #21: LDS dest linear, global source
  // pre-swizzled col_byte ^= (row&7)<<4). Two 8KB issues per 16KB half-tile.
  int row_[2], sc_[2];
#pragma unroll
  for (int it = 0; it < 2; ++it) {
    int o = it * 8192 + wv * 1024 + lane * 16;
    row_[it] = o >> 7;                                    // 0..127
    sc_[it]  = ((o & 127) ^ ((row_[it] & 7) << 4)) >> 1;  // element col
  }
  const bf16* pA[2][2];
  const bf16* pB[2][2];
#pragma unroll
  for (int h = 0; h < 2; ++h)
#pragma unroll
    for (int it = 0; it < 2; ++it) {
      pA[h][it] = A  + (size_t)(bm * 256 + h * 128 + row_[it]) * 1024 + sc_[it];
      pB[h][it] = Bm + (size_t)(bn * 256 + h * 128 + row_[it]) * 1024 + sc_[it];
    }
  const int lds0 = wv * 512;          // ushort offset, wave-uniform (no lane)
  const int lds1 = 4096 + wv * 512;

  // fragment read offsets (read-side swizzle)
  const int qoff  = quad * 8;
  const int swx   = (l16 & 7) << 3;
  const int aoffc = wm * 8192 + l16 * 64;
  const int boffc = (wn >> 1) * 8192 + ((wn & 1) * 64 + l16) * 64;

  short8 breg[4][2];

  // prologue: A(0),B(0) -> slot0; B(1) -> slot1  (12 loads/thread)
  STAGE_A(0, 0, 0); STAGE_A(0, 1, 0);
  STAGE_B(0, 0, 0); STAGE_B(0, 1, 0);
  STAGE_B(1, 0, 1); STAGE_B(1, 1, 1);
  asm volatile("s_waitcnt vmcnt(4)" ::: "memory");   // A(0),B(0) landed
  __builtin_amdgcn_s_barrier();

#pragma unroll 1
  for (int i = 0; i < 8; ++i) {
    const int t0 = 2 * i;
    const bool st = (i < 7);
    // P1-P4: consume K-tile t0 (slot0)
    PHASE(0, 0, STAGE_A(t0 + 1, 0, 1), (void)0);
    PHASE(1, 0, STAGE_A(t0 + 1, 1, 1), (void)0);
    PHASE(2, 0, if (st) STAGE_B(t0 + 2, 0, 0), (void)0);
    PHASE(3, 0, if (st) STAGE_B(t0 + 2, 1, 0), VMCNT_T);
    // P5-P8: consume K-tile t0+1 (slot1)
    PHASE(0, 1, if (st) STAGE_A(t0 + 2, 0, 0), (void)0);
    PHASE(1, 1, if (st) STAGE_A(t0 + 2, 1, 0), (void)0);
    PHASE(2, 1, if (st) STAGE_B(t0 + 3, 0, 1), (void)0);
    PHASE(3, 1, if (st) STAGE_B(t0 + 3, 1, 1), VMCNT_T);
  }

  // epilogue: QKV split. 1024%256==0 -> each bn-block in one region.
  const int region = bn >> 2;          // 0:Q 1:K 2:V
  if (region < 2) {
    bf16* dst = region == 0 ? Qp : Kp;
#pragma unroll
    for (int nj = 0; nj < 4; ++nj) {
      const int colg = bn * 256 + wn * 64 + nj * 16 + l16;
      const int colr = colg & 1023;
      const float bv = __bfloat162float(bias[colg]);
#pragma unroll
      for (int mi = 0; mi < 8; ++mi)
#pragma unroll
        for (int r = 0; r < 4; ++r) {
          int rowg = bm * 256 + wm * 128 + mi * 16 + quad * 4 + r;
          dst[(size_t)rowg * 1024 + colr] = __float2bfloat16(acc[mi][nj][r] + bv);
        }
    }
  } else {
    // V transposed: Vt[(b*16+h)<<16 | d*1024 | t], r-packed b64 stores
#pragma unroll
    for (int nj = 0; nj < 4; ++nj) {
      const int colg = bn * 256 + wn * 64 + nj * 16 + l16;
      const int d  = colg & 63;
      const int hh = (colg >> 6) & 15;
      const float bv = __bfloat162float(bias[colg]);
#pragma unroll
      for (int mi = 0; mi < 8; ++mi) {
        int rowg0 = bm * 256 + wm * 128 + mi * 16 + quad * 4;
        int bb = rowg0 >> 10, t0v = rowg0 & 1023;
        short4v pk;
#pragma unroll
        for (int r = 0; r < 4; ++r) pk[r] = (short)f2b_bits(acc[mi][nj][r] + bv);
        *(short4v*)&Vt[((size_t)(bb * 16 + hh) << 16) + ((size_t)d << 10) + t0v] = pk;
      }
    }
  }
}

// ---------------------------------------------------------------------------
// GEMM3 (R13-proven): C = A*Bm^T + bias, fp32 out. 128x128 tile, BK=64,
// 512 threads: 8 waves x (32x64). dbuf, counted vmcnt(4), raw barriers,
// T2 swizzle, L2-aware XCD-chunk traversal.
// ---------------------------------------------------------------------------
__global__ __launch_bounds__(512)
void gemm_bt_bias_f32(const bf16* __restrict__ A, const bf16* __restrict__ Bm,
                      const bf16* __restrict__ bias, float* __restrict__ C0,
                      int M, int N, int K)
{
  __shared__ __align__(16) unsigned short sA[2][128 * 64];
  __shared__ __align__(16) unsigned short sB[2][128 * 64];

  const int tid  = threadIdx.x;
  const int lane = tid & 63;
  const int wv   = tid >> 6;
  const int quad = lane >> 4;
  const int l16  = lane & 15;
  const int wm   = wv >> 1;
  const int wn   = wv & 1;

  const int gx   = gridDim.x;
  const int nwg  = gx * gridDim.y;
  const int bidl = blockIdx.y * gx + blockIdx.x;
  const int xcd  = bidl & 7;
  const int c    = bidl >> 3;
  const int cpx  = nwg >> 3;
  const int R    = cpx / gx;
  const int nb   = c / (R * 4);
  const int rem  = c % (R * 4);
  const int bm   = xcd * R + (rem >> 2);
  const int bn   = nb * 4 + (rem & 3);

  floatx4 acc[2][4];
#pragma unroll
  for (int i = 0; i < 2; ++i)
#pragma unroll
    for (int j = 0; j < 4; ++j) acc[i][j] = (floatx4){0.f, 0.f, 0.f, 0.f};

  const int o_base = wv * 1024 + lane * 16;
  const bf16* gA[2];
  const bf16* gB[2];
#pragma unroll
  for (int it = 0; it < 2; ++it) {
    int o   = it * 8192 + o_base;
    int row = o >> 7;
    int col = ((o & 127) ^ ((row & 7) << 4)) >> 1;
    gA[it] = A  + (size_t)(bm * 128 + row) * K + col;
    gB[it] = Bm + (size_t)(bn * 128 + row) * K + col;
  }

  const int NT = K >> 6;
#pragma unroll
  for (int it = 0; it < 2; ++it)
    gl2lds16(gA[it], &sA[0][(it * 8192 + wv * 1024) >> 1]);
#pragma unroll
  for (int it = 0; it < 2; ++it)
    gl2lds16(gB[it], &sB[0][(it * 8192 + wv * 1024) >> 1]);

  const int swx = (l16 & 7) << 3;

  for (int t = 0; t < NT; ++t) {
    const int s = t & 1;
    if (t + 1 < NT) {
#pragma unroll
      for (int it = 0; it < 2; ++it)
        gl2lds16(gA[it] + (size_t)(t + 1) * 64, &sA[s ^ 1][(it * 8192 + wv * 1024) >> 1]);
#pragma unroll
      for (int it = 0; it < 2; ++it)
        gl2lds16(gB[it] + (size_t)(t + 1) * 64, &sB[s ^ 1][(it * 8192 + wv * 1024) >> 1]);
      __builtin_amdgcn_sched_barrier(0);
      asm volatile("s_waitcnt vmcnt(4)" ::: "memory");
    } else {
      asm volatile("s_waitcnt vmcnt(0)" ::: "memory");
    }
    __builtin_amdgcn_s_barrier();
    __builtin_amdgcn_sched_barrier(0);

#pragma unroll
    for (int kk = 0; kk < 64; kk += 32) {
      short8 a_[2], b_[4];
#pragma unroll
      for (int i = 0; i < 2; ++i)
        a_[i] = *(const short8*)&sA[s][(wm * 32 + i * 16 + l16) * 64 + ((kk + quad * 8) ^ swx)];
#pragma unroll
      for (int j = 0; j < 4; ++j)
        b_[j] = *(const short8*)&sB[s][(wn * 64 + j * 16 + l16) * 64 + ((kk + quad * 8) ^ swx)];
#pragma unroll
      for (int i = 0; i < 2; ++i)
#pragma unroll
        for (int j = 0; j < 4; ++j)
          acc[i][j] = __builtin_amdgcn_mfma_f32_16x16x32_bf16(a_[i], b_[j], acc[i][j], 0, 0, 0);
    }

    __builtin_amdgcn_sched_barrier(0);
    __builtin_amdgcn_s_barrier();
  }

#pragma unroll
  for (int j = 0; j < 4; ++j) {
    const int colg = bn * 128 + wn * 64 + j * 16 + l16;
    const float bv = __bfloat162float(bias[colg]);
#pragma unroll
    for (int i = 0; i < 2; ++i)
#pragma unroll
      for (int r = 0; r < 4; ++r) {
        int rowg = bm * 128 + wm * 32 + i * 16 + quad * 4 + r;
        C0[(size_t)rowg * N + colg] = acc[i][j][r] + bv;
      }
  }
}

// ---------------------------------------------------------------------------
// Fused attention. grid = (16, 8, 8), 512 threads (8 waves x 16 rows),
// LDS 36.0KB. Work swizzle: bid -> b=bid&7 (XCD), h=(bid>>3)&15 (fastest,
// adj-sharing blocks contiguous on one XCD), qt=bid>>7.
// Q fragments in registers (loop-invariant). K and V^T register-staged into
// stride-72 LDS (balanced banks), software-pipelined across kt.
// sigma(n)=(n&15)*4+(n>>4) on K rows => logical score col = l16*4+j:
// float4 adj/mask loads. p=fast_exp2(clamp(fma(sacc, avc, off))) with
// avc = av*cjv (folded scale); pack via v_cvt_pk_bf16_f32 (RNE) pairs,
// b64 sP stores. L row-sums via ones-column MFMA accumulated across kt.
// ---------------------------------------------------------------------------
__global__ __launch_bounds__(512)
void attn_fused(const bf16* __restrict__ Qp, const bf16* __restrict__ Kp,
                const bf16* __restrict__ Vt, const float* __restrict__ adj,
                const float* __restrict__ mask, bf16* __restrict__ aout)
{
  __shared__ __align__(16) unsigned short sK[64 * 72];
  __shared__ __align__(16) unsigned short sVT[64 * 72];
  __shared__ __align__(16) unsigned short sP[128 * 72];

  const int tid  = threadIdx.x;
  const int lane = tid & 63;
  const int wv   = tid >> 6;          // 0..7
  const int quad = lane >> 4;
  const int l16  = lane & 15;

  // work swizzle: adj-sharing (b,qt) groups contiguous per XCD, K/V[b] local
  const int bid  = blockIdx.x + 16 * (blockIdx.y + 8 * blockIdx.z);
  const int b    = bid & 7;
  const int slot = bid >> 3;
  const int h    = slot & 15;
  const int qt   = slot >> 4;

  // Q fragments: rows qt*128 + wv*16 + l16, k = kk + quad*8 + [0..7]
  const bf16* qbase = Qp + (size_t)(b * T_ + qt * 128 + wv * 16 + l16) * 1024 + h * 64 + quad * 8;
  const short8 aq0 = *(const short8*)qbase;
  const short8 aq1 = *(const short8*)(qbase + 32);

  // staging: 512 threads cover 64 rows x 8 chunks, one 16B chunk each
  const int srow  = tid >> 3;                          // 0..63
  const int chunk = (tid & 7) * 8;
  const int sig = ((srow & 15) << 2) | (srow >> 4);    // token offset for sK row
  const bf16* kb = Kp + (size_t)(b * T_ + sig) * 1024 + h * 64 + chunk;  // +kt<<16
  const bf16* vb = Vt + ((size_t)(b * 16 + h) << 16) + ((size_t)srow << 10) + chunk; // +kt*64

  // adj/mask row pointers
  const float* mb = mask + b * T_ + l16 * 4;
  const float* adjr[4];
#pragma unroll
  for (int r = 0; r < 4; ++r)
    adjr[r] = adj + ((size_t)b * T_ + qt * 128 + wv * 16 + quad * 4 + r) * T_ + l16 * 4;

  // preload kt=0 staging registers
  short8 kr = *(const short8*)kb;
  short8 vr = *(const short8*)vb;

  // bf16 1.0 fragment for L row-sums via MFMA
  short8 ones8;
#pragma unroll
  for (int i = 0; i < 8; ++i) ones8[i] = (short)0x3F80;

  floatx4 oacc[4];
#pragma unroll
  for (int d = 0; d < 4; ++d) oacc[d] = (floatx4){0.f, 0.f, 0.f, 0.f};
  floatx4 Lacc = (floatx4){0.f, 0.f, 0.f, 0.f};

  const float SC = 0.125f * 1.44269504088896f;   // (1/sqrt(dh)) * log2(e)

  for (int kt = 0; kt < 16; ++kt) {
    // adj/mask for this tile (logical cols kt*64 + l16*4 + {0..3})
    floatx4 av[4];
    floatx4 mk4 = *(const floatx4*)(mb + kt * 64);
#pragma unroll
    for (int r = 0; r < 4; ++r) av[r] = *(const floatx4*)(adjr[r] + kt * 64);
    floatx4 cjv, offv;
#pragma unroll
    for (int j = 0; j < 4; ++j) {
      cjv[j]  = mk4[j] * SC;
      offv[j] = (mk4[j] == 0.f) ? -1e30f : 0.f;
    }

    __syncthreads();   // sync1: all waves done reading sK/sVT of prev kt
    *(short8*)&sK [srow * 72 + chunk] = kr;
    *(short8*)&sVT[srow * 72 + chunk] = vr;
    __syncthreads();   // sync2: staging visible

    // prefetch next kt's staging registers (VMEM overlaps compute below)
    {
      int nk = kt < 15 ? kt + 1 : 15;
      kr = *(const short8*)(kb + ((size_t)nk << 16));
      vr = *(const short8*)(vb + (nk << 6));
    }

    // S = Q K^T  (sacc[j][r]: row wv*16+quad*4+r, logical col l16*4+j)
    floatx4 sacc[4];
#pragma unroll
    for (int j = 0; j < 4; ++j) sacc[j] = (floatx4){0.f, 0.f, 0.f, 0.f};
    __builtin_amdgcn_s_setprio(1);
#pragma unroll
    for (int kk = 0; kk < 64; kk += 32) {
      short8 aq = kk ? aq1 : aq0;
#pragma unroll
      for (int j = 0; j < 4; ++j) {
        short8 bk = *(const short8*)&sK[(j * 16 + l16) * 72 + kk + quad * 8];
        sacc[j] = __builtin_amdgcn_mfma_f32_16x16x32_bf16(aq, bk, sacc[j], 0, 0, 0);
      }
    }
    __builtin_amdgcn_s_setprio(0);

    // p = fast_exp2(clamp(fma(sacc, avc, off))); pack via v_cvt_pk_bf16_f32
#pragma unroll
    for (int r = 0; r < 4; ++r) {
      floatx4 avc = av[r] * cjv;      // folded adj*mask*SC (pk-pairable)
      float p[4];
#pragma unroll
      for (int j = 0; j < 4; ++j) {
        float z = fminf(fmaf(sacc[j][r], avc[j], offv[j]), 100.f);
        p[j] = fast_exp2(z);
      }
      unsigned w0, w1;
      asm("v_cvt_pk_bf16_f32 %0, %1, %2" : "=v"(w0) : "v"(p[0]), "v"(p[1]));
      asm("v_cvt_pk_bf16_f32 %0, %1, %2" : "=v"(w1) : "v"(p[2]), "v"(p[3]));
      uint2v pw; pw[0] = w0; pw[1] = w1;
      *(uint2v*)&sP[(wv * 16 + quad * 4 + r) * 72 + l16 * 4] = pw;
    }

    // sP rows wave-local; same-wave DS is HW-ordered. Stop compiler reorder:
    __asm__ __volatile__("" ::: "memory");

    // O += P V ; L += P * ones
    __builtin_amdgcn_s_setprio(1);
#pragma unroll
    for (int kk = 0; kk < 64; kk += 32) {
      short8 ap = *(const short8*)&sP[(wv * 16 + l16) * 72 + kk + quad * 8];
      Lacc = __builtin_amdgcn_mfma_f32_16x16x32_bf16(ap, ones8, Lacc, 0, 0, 0);
#pragma unroll
      for (int d = 0; d < 4; ++d) {
        short8 bv = *(const short8*)&sVT[(d * 16 + l16) * 72 + kk + quad * 8];
        oacc[d] = __builtin_amdgcn_mfma_f32_16x16x32_bf16(ap, bv, oacc[d], 0, 0, 0);
      }
    }
    __builtin_amdgcn_s_setprio(0);
  }

  // epilogue: Lacc[r] already holds the full row sum (every col identical)
#pragma unroll
  for (int d = 0; d < 4; ++d) {
#pragma unroll
    for (int r = 0; r < 4; ++r) {
      int qrow = qt * 128 + wv * 16 + quad * 4 + r;
      float val = oacc[d][r] / (Lacc[r] + 1e-13f);
      aout[(size_t)(b * T_ + qrow) * 1024 + h * 64 + d * 16 + l16] = __float2bfloat16(val);
    }
  }
}

// ---------------------------------------------------------------------------
extern "C" void kernel_launch(void* const* d_in, const int* in_sizes, int n_in,
                              void* d_out, int out_size, void* d_ws, size_t ws_size,
                              hipStream_t stream) {
  const float* inputs = (const float*)d_in[0];   // [8,1024,1024]
  const float* mask   = (const float*)d_in[1];   // [8,1024]
  const float* adj    = (const float*)d_in[2];   // [8,1024,1024]
  const float* W_qkv  = (const float*)d_in[3];   // [3072,1024]
  const float* b_qkv  = (const float*)d_in[4];   // [3072]
  const float* W_out  = (const float*)d_in[5];   // [1024,1024]
  const float* b_out  = (const float*)d_in[6];   // [1024]

  const size_t SEG = (size_t)8192 * 1024;        // 16 MiB bf16 segments
  bf16* Qp   = (bf16*)d_ws;                      // @0
  bf16* Kp   = Qp + SEG;                         // @16MiB
  bf16* Vt   = Kp + SEG;                         // @32MiB
  bf16* aout = Vt + SEG;                         // @48MiB
  bf16* wo_bf = Qp;                              // Qp dead after attn
  bf16* bo_bf = Qp + (size_t)1024 * 1024;

  // d_out as phase-1 scratch (32MiB fp32 region, dead until GEMM3)
  bf16* ib_bf = (bf16*)d_out;                    // 16MiB
  bf16* wq_bf = ib_bf + SEG;                     // 6MiB
  bf16* bq_bf = wq_bf + (size_t)3072 * 1024;

  dim3 blk(256);
  cvt_f32_bf16<<<dim3(8192 * 1024 / 4 / 256), blk, 0, stream>>>(inputs, ib_bf, 8192 * 1024);
  cvt_f32_bf16<<<dim3(3072 * 1024 / 4 / 256), blk, 0, stream>>>(W_qkv, wq_bf, 3072 * 1024);
  cvt_f32_bf16<<<dim3(3), blk, 0, stream>>>(b_qkv, bq_bf, 3072);
  // QKV projection: 256^2 8-phase kernel
  gemm_qkv_8phase<<<dim3(PROJW / 256, (B_ * T_) / 256), dim3(512), 0, stream>>>(
      ib_bf, wq_bf, bq_bf, Qp, Kp, Vt);
  // fused attention (512 threads, 128 q-rows/block)
  attn_fused<<<dim3(H_, T_ / 128, B_), dim3(512), 0, stream>>>(Qp, Kp, Vt, adj, mask, aout);
  // output projection weights into dead Qp region
  cvt_f32_bf16<<<dim3(1024 * 1024 / 4 / 256), blk, 0, stream>>>(W_out, wo_bf, 1024 * 1024);
  cvt_f32_bf16<<<dim3(1), blk, 0, stream>>>(b_out, bo_bf, 1024);
  // output projection: C fp32 -> d_out (R13-proven 2-phase kernel)
  gemm_bt_bias_f32<<<dim3(D_ / 128, (B_ * T_) / 128), dim3(512), 0, stream>>>(
      aout, wo_bf, bo_bf, (float*)d_out, B_ * T_, D_, D_);
}